// Round 12
// baseline (99.552 us; speedup 1.0000x reference)
//
#include <hip/hip_runtime.h>
#include <math.h>

#define B_   4
#define L_   4096
#define C_   512
#define DM_  1024
#define HID_ 128
#define M_   (B_*L_)    // 16384
#define NC_  256        // chunks of 16 rows
#define CT_  16

typedef __attribute__((ext_vector_type(8))) short short8;
typedef __attribute__((ext_vector_type(4))) float f32x4;

__device__ __forceinline__ unsigned short f2bf(float f) {
  unsigned u = __float_as_uint(f);
  u += 0x7fffu + ((u >> 16) & 1u);
  return (unsigned short)(u >> 16);
}

// wrap(-theta) into (-pi, pi] == atan2(sin(-t), cos(-t))
__device__ __forceinline__ float wrap_neg(float th) {
  return 6.283185307179586f * rintf(th * 0.15915494309189535f) - th;
}

// ---- prep: transpose+cast weights to bf16 [n][k]
__global__ __launch_bounds__(256) void k_prep(const float* __restrict__ W1,
                                              const float* __restrict__ W2,
                                              unsigned short* __restrict__ W1T,
                                              unsigned short* __restrict__ W2T) {
  int idx = blockIdx.x * 256 + threadIdx.x;
  if (idx < DM_ * HID_) {
    int n = idx >> 10, k = idx & 1023;
    W1T[idx] = f2bf(W1[(size_t)k * HID_ + n]);
  }
  int i2 = idx - DM_ * HID_;
  if (i2 >= 0 && i2 < HID_ * C_) {
    int n = i2 >> 7, k = i2 & 127;
    W2T[i2] = f2bf(W2[(size_t)k * C_ + n]);
  }
}

// ---- k_mega: BM=16, 1024 blocks x 256 thr (4 waves). ALL X (16x f32x4) and theta
//      (32 scalars) loads issued at kernel entry -> latency paid once per block.
//      Phase1: dbuf A, 1 barrier/iter, zero vmem waits in loop; W1T from L2 1-ahead.
//      Phase2: zero barriers; W2T from L2 1-ahead; epilogue Pi/K/R + 16-row
//      affine composite via kg-butterfly.
// LDS: A dbuf [0,4096) 2x(16x64 bf16 swizzled), H [4096,8448) 16 x 272B
__global__ __launch_bounds__(256) void k_mega(const float* __restrict__ X,
                                              const unsigned short* __restrict__ W1T,
                                              const float* __restrict__ b1,
                                              const unsigned short* __restrict__ W2T,
                                              const float* __restrict__ b2,
                                              const float* __restrict__ logPi,
                                              const float* __restrict__ theta,
                                              float* __restrict__ out1,
                                              float* __restrict__ out2,
                                              float* __restrict__ out3,
                                              float* __restrict__ Ab,
                                              float* __restrict__ Ub) {
  __shared__ char lds[8448];
  const int tid  = threadIdx.x;
  const int m0   = blockIdx.x * 16;
  const int lane = tid & 63;
  const int wc   = tid >> 6;       // wave = col group 0..3
  const int fr   = lane & 15;
  const int kg   = lane >> 4;      // 0..3

  // ---- issue ALL global loads for this block up front ----
  const int srow = tid >> 4;       // 0..15
  const int sk4  = tid & 15;       // 0..15
  const float* xsrc = X + (size_t)(m0 + srow) * DM_ + sk4 * 4;
  f32x4 xr[16];
#pragma unroll
  for (int it = 0; it < 16; ++it)
    xr[it] = __builtin_nontemporal_load((const f32x4*)(xsrc + it * 64));

  const int colbase = wc * 16 + fr;
  const size_t throw0 = (size_t)(m0 + kg * 4) * C_;
  float thr[8][4];
#pragma unroll
  for (int nc = 0; nc < 8; ++nc)
#pragma unroll
    for (int r = 0; r < 4; ++r)
      thr[nc][r] = theta[throw0 + (size_t)r * C_ + nc * 64 + colbase];

  // ---------------- phase 1: H = gelu(X @ W1 + b1), 16x128 ----------------
  char* swr = lds + srow * 128 + ((sk4 << 3) ^ ((srow & 7) << 4));
  const unsigned short* w1p0 = W1T + (size_t)(wc * 32 + fr) * DM_ + kg * 8;
  const unsigned short* w1p1 = W1T + (size_t)(wc * 32 + 16 + fr) * DM_ + kg * 8;

  f32x4 acc0 = {0.f, 0.f, 0.f, 0.f};
  f32x4 acc1 = {0.f, 0.f, 0.f, 0.f};

  {  // prologue: write buf0 from xr[0]
    uint2 pk = { f2bf(xr[0][0]) | ((unsigned)f2bf(xr[0][1]) << 16),
                 f2bf(xr[0][2]) | ((unsigned)f2bf(xr[0][3]) << 16) };
    *(uint2*)swr = pk;
  }
  short8 bc[4], bn[4];
  bc[0] = *(const short8*)(w1p0);
  bc[1] = *(const short8*)(w1p1);
  bc[2] = *(const short8*)(w1p0 + 32);
  bc[3] = *(const short8*)(w1p1 + 32);
  __syncthreads();

  const int arow = fr;
  char* ard = lds + arow * 128;

#pragma unroll
  for (int it = 0; it < 16; ++it) {
    const int cur = it & 1;
    if (it < 15) {
      // next W1T frags (L2) + next A buffer from registers
      const unsigned short* p0 = w1p0 + (it + 1) * 64;
      const unsigned short* p1 = w1p1 + (it + 1) * 64;
      bn[0] = *(const short8*)(p0);
      bn[1] = *(const short8*)(p1);
      bn[2] = *(const short8*)(p0 + 32);
      bn[3] = *(const short8*)(p1 + 32);
      uint2 pk = { f2bf(xr[it + 1][0]) | ((unsigned)f2bf(xr[it + 1][1]) << 16),
                   f2bf(xr[it + 1][2]) | ((unsigned)f2bf(xr[it + 1][3]) << 16) };
      *(uint2*)(swr + (1 - cur) * 2048) = pk;
    }
#pragma unroll
    for (int ks = 0; ks < 2; ++ks) {
      short8 a = *(const short8*)(ard + cur * 2048 +
                                  (((ks * 4 + kg) << 4) ^ ((arow & 7) << 4)));
      acc0 = __builtin_amdgcn_mfma_f32_16x16x32_bf16(a, bc[ks * 2 + 0], acc0, 0, 0, 0);
      acc1 = __builtin_amdgcn_mfma_f32_16x16x32_bf16(a, bc[ks * 2 + 1], acc1, 0, 0, 0);
    }
    if (it < 15) {
      __syncthreads();
#pragma unroll
      for (int q = 0; q < 4; ++q) bc[q] = bn[q];
    }
  }

  // H epilogue -> LDS [4096,8448), row stride 272 B
#pragma unroll
  for (int j = 0; j < 2; ++j) {
    int col = wc * 32 + j * 16 + fr;
    float bb = b1[col];
    f32x4 av = (j == 0) ? acc0 : acc1;
#pragma unroll
    for (int r = 0; r < 4; ++r) {
      int row = kg * 4 + r;
      float x = av[r] + bb;
      float g = 0.5f * x * (1.0f + erff(x * 0.70710678f));
      *(unsigned short*)(lds + 4096 + row * 272 + col * 2) = f2bf(g);
    }
  }
  __syncthreads();

  // ---------------- phase 2: zero barriers ----------------
  const int bidx = blockIdx.x >> 8;
  const int ch   = blockIdx.x & 255;
  const size_t chbase = ((size_t)(bidx * NC_ + ch)) * C_;
  const unsigned short* w2p = W2T + (size_t)colbase * HID_ + kg * 8;
  const char* hrd = lds + 4096 + fr * 272;

  short8 c2[4], n2[4];
#pragma unroll
  for (int ks = 0; ks < 4; ++ks) c2[ks] = *(const short8*)(w2p + ks * 32);

#pragma unroll
  for (int nc = 0; nc < 8; ++nc) {
    const int col = nc * 64 + colbase;
    if (nc < 7) {
#pragma unroll
      for (int ks = 0; ks < 4; ++ks)
        n2[ks] = *(const short8*)(w2p + (size_t)(nc + 1) * 64 * HID_ + ks * 32);
    }
    float Pi = expf(logPi[col]);
    float bb = b2[col];

    f32x4 a2 = {0.f, 0.f, 0.f, 0.f};
#pragma unroll
    for (int ks = 0; ks < 4; ++ks) {
      short8 a = *(const short8*)(hrd + ks * 64 + kg * 16);
      a2 = __builtin_amdgcn_mfma_f32_16x16x32_bf16(a, c2[ks], a2, 0, 0, 0);
    }

    float A = 1.f, U = 0.f;
#pragma unroll
    for (int r = 0; r < 4; ++r) {
      int row = m0 + kg * 4 + r;
      float lr = a2[r] + bb;
      lr = fminf(5.0f, fmaxf(-5.0f, lr));
      float R = expf(lr);
      float K = Pi / fmaxf(Pi + R, 1e-8f);
      size_t o = (size_t)row * C_ + col;
      __builtin_nontemporal_store(Pi, &out1[o]);
      out2[o] = K;                       // re-read by scan3
      __builtin_nontemporal_store(R, &out3[o]);
      float nu = wrap_neg(thr[nc][r]);
      float a = 1.f - K;
      U = a * U + K * nu;
      A = a * A;
    }
    // ordered combine across kg lanes (butterfly)
    float oA = __shfl_xor(A, 16), oU = __shfl_xor(U, 16);
    if ((kg & 1) == 0) { U = oA * U + oU; A = oA * A; }
    else               { U = A * oU + U;  A = A * oA; }
    oA = __shfl_xor(A, 32); oU = __shfl_xor(U, 32);
    if ((kg & 2) == 0) { U = oA * U + oU; A = oA * A; }
    else               { U = A * oU + U;  A = A * oA; }
    if (kg == 0) { Ab[chbase + col] = A; Ub[chbase + col] = U; }

    if (nc < 7) {
#pragma unroll
      for (int ks = 0; ks < 4; ++ks) c2[ks] = n2[ks];
    }
  }
}

// ---- scan2: block-level prefix over 256 chunks for 16 channels
__global__ __launch_bounds__(256) void k_scan2(const float* __restrict__ Ab,
                                               const float* __restrict__ Ub,
                                               float* __restrict__ D0) {
  __shared__ float cA[16][17], cU[16][17], carry[16][17];
  const int tid = threadIdx.x;
  const int b   = blockIdx.x >> 5;
  const int c0  = (blockIdx.x & 31) * 16;
  const int c_l = tid & 15, s = tid >> 4;   // 16 segs x 16 chunks
  const int c   = c0 + c_l;
  float A = 1.f, U = 0.f;
#pragma unroll
  for (int k = 0; k < 16; ++k) {
    size_t o = ((size_t)(b * NC_ + s * 16 + k)) * C_ + c;
    float a = Ab[o], u = Ub[o];
    U = a * U + u; A *= a;
  }
  cA[s][c_l] = A; cU[s][c_l] = U;
  __syncthreads();
  if (tid < 16) {
    float P = 0.f;
#pragma unroll
    for (int ss = 0; ss < 16; ++ss) {
      carry[ss][tid] = P;
      P = cA[ss][tid] * P + cU[ss][tid];
    }
  }
  __syncthreads();
  float d = carry[s][c_l];
#pragma unroll
  for (int k = 0; k < 16; ++k) {
    size_t o = ((size_t)(b * NC_ + s * 16 + k)) * C_ + c;
    D0[o] = d;
    d = Ab[o] * d + Ub[o];
  }
}

// ---- scan3: apply carry, out0 = theta + d. Thread = 4 channels x 16-row chunk.
// 131072 threads total = 512 blocks x 256.
__global__ __launch_bounds__(256) void k_scan3(const float* __restrict__ Kv,
                                               const float* __restrict__ theta,
                                               const float* __restrict__ D0,
                                               float* __restrict__ out0) {
  const int g  = blockIdx.x * 256 + threadIdx.x;   // 0..131071
  const int cg = g & 127;                          // channel group (4 ch)
  const int ch = (g >> 7) & 255;
  const int b  = g >> 15;                          // 0..3
  const int c0 = cg * 4;
  size_t base = ((size_t)b * L_ + (size_t)ch * CT_) * C_ + c0;
  f32x4 d = *(const f32x4*)(D0 + ((size_t)(b * NC_ + ch)) * C_ + c0);
#pragma unroll 4
  for (int j = 0; j < CT_; ++j) {
    size_t idx = base + (size_t)j * C_;
    f32x4 k  = *(const f32x4*)(Kv + idx);
    f32x4 th = *(const f32x4*)(theta + idx);
    f32x4 o;
#pragma unroll
    for (int q = 0; q < 4; ++q) {
      float nu = wrap_neg(th[q]);
      d[q] = (1.f - k[q]) * d[q] + k[q] * nu;
      o[q] = th[q] + d[q];
    }
    __builtin_nontemporal_store(o, (f32x4*)(out0 + idx));
  }
}

extern "C" void kernel_launch(void* const* d_in, const int* in_sizes, int n_in,
                              void* d_out, int out_size, void* d_ws, size_t ws_size,
                              hipStream_t stream) {
  const float* theta = (const float*)d_in[0];
  const float* X     = (const float*)d_in[1];
  const float* logPi = (const float*)d_in[2];
  const float* W1    = (const float*)d_in[3];
  const float* b1    = (const float*)d_in[4];
  const float* W2    = (const float*)d_in[5];
  const float* b2    = (const float*)d_in[6];

  float* out = (float*)d_out;
  const size_t S = (size_t)M_ * C_;
  float* out0 = out;
  float* out1 = out + S;
  float* out2 = out + 2 * S;
  float* out3 = out + 3 * S;

  unsigned short* W1T = (unsigned short*)d_ws;           // 131072 ush
  unsigned short* W2T = W1T + (size_t)DM_ * HID_;        // 65536 ush
  float* Ab = (float*)(W2T + (size_t)HID_ * C_);         // B*NC*C f32 each (2 MiB)
  float* Ub = Ab + (size_t)B_ * NC_ * C_;
  float* D0 = Ub + (size_t)B_ * NC_ * C_;

  hipLaunchKernelGGL(k_prep, dim3(768), dim3(256), 0, stream, W1, W2, W1T, W2T);
  hipLaunchKernelGGL(k_mega, dim3(M_ / 16), dim3(256), 0, stream,
                     X, W1T, b1, W2T, b2, logPi, theta, out1, out2, out3, Ab, Ub);
  hipLaunchKernelGGL(k_scan2, dim3(B_ * 32), dim3(256), 0, stream, Ab, Ub, D0);
  hipLaunchKernelGGL(k_scan3, dim3(M_ * C_ / 64 / 256), dim3(256), 0, stream,
                     out2, theta, D0, out0);
}

// Round 13
// 96.388 us; speedup vs baseline: 1.0328x; 1.0328x over previous
//
#include <hip/hip_runtime.h>
#include <math.h>

#define B_   4
#define L_   4096
#define C_   512
#define DM_  1024
#define HID_ 128
#define M_   (B_*L_)    // 16384
#define NC_  256        // chunks of 16 rows
#define CT_  16

typedef __attribute__((ext_vector_type(8))) short short8;
typedef __attribute__((ext_vector_type(4))) float f32x4;

__device__ __forceinline__ unsigned short f2bf(float f) {
  unsigned u = __float_as_uint(f);
  u += 0x7fffu + ((u >> 16) & 1u);
  return (unsigned short)(u >> 16);
}

// wrap(-theta) into (-pi, pi] == atan2(sin(-t), cos(-t))
__device__ __forceinline__ float wrap_neg(float th) {
  return 6.283185307179586f * rintf(th * 0.15915494309189535f) - th;
}

// ---- prep: transpose+cast weights to bf16 [n][k]
__global__ __launch_bounds__(256) void k_prep(const float* __restrict__ W1,
                                              const float* __restrict__ W2,
                                              unsigned short* __restrict__ W1T,
                                              unsigned short* __restrict__ W2T) {
  int idx = blockIdx.x * 256 + threadIdx.x;
  if (idx < DM_ * HID_) {
    int n = idx >> 10, k = idx & 1023;
    W1T[idx] = f2bf(W1[(size_t)k * HID_ + n]);
  }
  int i2 = idx - DM_ * HID_;
  if (i2 >= 0 && i2 < HID_ * C_) {
    int n = i2 >> 7, k = i2 & 127;
    W2T[i2] = f2bf(W2[(size_t)k * C_ + n]);
  }
}

// ---- k_mega: 1024 blocks x 512 thr (8 waves). Whole X tile (16x1024 bf16) staged
//      once (1 barrier). Phase1: wave w owns H cols [16w,16w+16), full K=1024 loop
//      independently (A from LDS, B from L2, NO barriers). 1 barrier after H.
//      Phase2: wave w owns out cols [64w,64w+64), zero barriers; writes K(out2),
//      R(out3) + 16-row affine composites via kg-butterfly. Pi/out1 moved to scan3.
// LDS: X [0,32768) 16 rows x 2048B swizzled; H [32768,37120) 16 x 272B
__global__ __launch_bounds__(512) void k_mega(const float* __restrict__ X,
                                              const unsigned short* __restrict__ W1T,
                                              const float* __restrict__ b1,
                                              const unsigned short* __restrict__ W2T,
                                              const float* __restrict__ b2,
                                              const float* __restrict__ logPi,
                                              const float* __restrict__ theta,
                                              float* __restrict__ out2,
                                              float* __restrict__ out3,
                                              float* __restrict__ Ab,
                                              float* __restrict__ Ub) {
  __shared__ char lds[37120];
  const int tid  = threadIdx.x;
  const int m0   = blockIdx.x * 16;
  const int lane = tid & 63;
  const int w    = tid >> 6;       // wave 0..7
  const int fr   = lane & 15;
  const int kg   = lane >> 4;      // 0..3

  // ---- stage whole X tile: 16 x 1024 f32 -> bf16 LDS (XOR-swizzled) ----
  {
    const int row = tid >> 5;            // 0..15
    const int c32 = tid & 31;            // 0..31
    const float* xsrc = X + (size_t)(m0 + row) * DM_ + c32 * 8;
    char* base = lds + row * 2048;
    const int sw = (row & 7) << 4;
    f32x4 xa[4], xb[4];
#pragma unroll
    for (int q = 0; q < 4; ++q) {
      xa[q] = __builtin_nontemporal_load((const f32x4*)(xsrc + q * 256));
      xb[q] = __builtin_nontemporal_load((const f32x4*)(xsrc + q * 256 + 4));
    }
#pragma unroll
    for (int q = 0; q < 4; ++q) {
      uint4 pk;
      pk.x = f2bf(xa[q][0]) | ((unsigned)f2bf(xa[q][1]) << 16);
      pk.y = f2bf(xa[q][2]) | ((unsigned)f2bf(xa[q][3]) << 16);
      pk.z = f2bf(xb[q][0]) | ((unsigned)f2bf(xb[q][1]) << 16);
      pk.w = f2bf(xb[q][2]) | ((unsigned)f2bf(xb[q][3]) << 16);
      *(uint4*)(base + ((c32 * 16 + q * 512) ^ sw)) = pk;
    }
  }
  __syncthreads();

  // ---- phase 1: H[0:16, w*16+fr] over K=1024, barrier-free per wave ----
  f32x4 acc = {0.f, 0.f, 0.f, 0.f};
  {
    const unsigned short* w1p = W1T + (size_t)(w * 16 + fr) * DM_ + kg * 8;
    const char* ar = lds + fr * 2048;
    const int asw = (fr & 7) << 4;
#pragma unroll
    for (int ks = 0; ks < 32; ++ks) {
      short8 b = *(const short8*)(w1p + ks * 32);
      short8 a = *(const short8*)(ar + ((ks * 64 + kg * 16) ^ asw));
      acc = __builtin_amdgcn_mfma_f32_16x16x32_bf16(a, b, acc, 0, 0, 0);
    }
  }
  // H epilogue -> LDS [32768,37120), row stride 272 B
  {
    int col = w * 16 + fr;
    float bb = b1[col];
#pragma unroll
    for (int r = 0; r < 4; ++r) {
      int row = kg * 4 + r;
      float x = acc[r] + bb;
      float g = 0.5f * x * (1.0f + erff(x * 0.70710678f));
      *(unsigned short*)(lds + 32768 + row * 272 + col * 2) = f2bf(g);
    }
  }
  __syncthreads();

  // ---- phase 2: wave w owns cols [64w, 64w+64), zero barriers ----
  const int bidx = blockIdx.x >> 8;
  const int ch   = blockIdx.x & 255;
  const size_t chbase = ((size_t)(bidx * NC_ + ch)) * C_;
  const char* hr = lds + 32768 + fr * 272;
  const size_t throw0 = (size_t)(m0 + kg * 4) * C_;

#pragma unroll
  for (int t = 0; t < 4; ++t) {
    const int col = w * 64 + t * 16 + fr;
    float th[4];
#pragma unroll
    for (int r = 0; r < 4; ++r)
      th[r] = theta[throw0 + (size_t)r * C_ + col];

    const unsigned short* w2p = W2T + (size_t)col * HID_ + kg * 8;
    f32x4 a2 = {0.f, 0.f, 0.f, 0.f};
#pragma unroll
    for (int ks = 0; ks < 4; ++ks) {
      short8 bfr = *(const short8*)(w2p + ks * 32);
      short8 afr = *(const short8*)(hr + ks * 64 + kg * 16);
      a2 = __builtin_amdgcn_mfma_f32_16x16x32_bf16(afr, bfr, a2, 0, 0, 0);
    }

    float Pi = expf(logPi[col]);
    float bb = b2[col];
    float A = 1.f, U = 0.f;
#pragma unroll
    for (int r = 0; r < 4; ++r) {
      int row = m0 + kg * 4 + r;
      float lr = a2[r] + bb;
      lr = fminf(5.0f, fmaxf(-5.0f, lr));
      float R = expf(lr);
      float K = Pi / fmaxf(Pi + R, 1e-8f);
      size_t o = (size_t)row * C_ + col;
      out2[o] = K;                       // re-read by scan3: keep in L3
      __builtin_nontemporal_store(R, &out3[o]);
      float nu = wrap_neg(th[r]);
      float a = 1.f - K;
      U = a * U + K * nu;
      A = a * A;
    }
    // ordered combine across kg lanes (butterfly)
    float oA = __shfl_xor(A, 16), oU = __shfl_xor(U, 16);
    if ((kg & 1) == 0) { U = oA * U + oU; A = oA * A; }
    else               { U = A * oU + U;  A = A * oA; }
    oA = __shfl_xor(A, 32); oU = __shfl_xor(U, 32);
    if ((kg & 2) == 0) { U = oA * U + oU; A = oA * A; }
    else               { U = A * oU + U;  A = A * oA; }
    if (kg == 0) { Ab[chbase + col] = A; Ub[chbase + col] = U; }
  }
}

// ---- scan2: block-level prefix over 256 chunks for 16 channels
__global__ __launch_bounds__(256) void k_scan2(const float* __restrict__ Ab,
                                               const float* __restrict__ Ub,
                                               float* __restrict__ D0) {
  __shared__ float cA[16][17], cU[16][17], carry[16][17];
  const int tid = threadIdx.x;
  const int b   = blockIdx.x >> 5;
  const int c0  = (blockIdx.x & 31) * 16;
  const int c_l = tid & 15, s = tid >> 4;   // 16 segs x 16 chunks
  const int c   = c0 + c_l;
  float A = 1.f, U = 0.f;
#pragma unroll
  for (int k = 0; k < 16; ++k) {
    size_t o = ((size_t)(b * NC_ + s * 16 + k)) * C_ + c;
    float a = Ab[o], u = Ub[o];
    U = a * U + u; A *= a;
  }
  cA[s][c_l] = A; cU[s][c_l] = U;
  __syncthreads();
  if (tid < 16) {
    float P = 0.f;
#pragma unroll
    for (int ss = 0; ss < 16; ++ss) {
      carry[ss][tid] = P;
      P = cA[ss][tid] * P + cU[ss][tid];
    }
  }
  __syncthreads();
  float d = carry[s][c_l];
#pragma unroll
  for (int k = 0; k < 16; ++k) {
    size_t o = ((size_t)(b * NC_ + s * 16 + k)) * C_ + c;
    D0[o] = d;
    d = Ab[o] * d + Ub[o];
  }
}

// ---- scan3: apply carry, out0 = theta + d; also out1 = Pi (broadcast).
// 512 blocks x 256 thr; thread = 4 channels x 16-row chunk.
__global__ __launch_bounds__(256) void k_scan3(const float* __restrict__ Kv,
                                               const float* __restrict__ theta,
                                               const float* __restrict__ D0,
                                               const float* __restrict__ logPi,
                                               float* __restrict__ out0,
                                               float* __restrict__ out1) {
  const int g  = blockIdx.x * 256 + threadIdx.x;   // 0..131071
  const int cg = g & 127;                          // channel group (4 ch)
  const int ch = (g >> 7) & 255;
  const int b  = g >> 15;                          // 0..3
  const int c0 = cg * 4;
  f32x4 lp = *(const f32x4*)(logPi + c0);
  f32x4 Pi4;
#pragma unroll
  for (int q = 0; q < 4; ++q) Pi4[q] = expf(lp[q]);
  size_t base = ((size_t)b * L_ + (size_t)ch * CT_) * C_ + c0;
  f32x4 d = *(const f32x4*)(D0 + ((size_t)(b * NC_ + ch)) * C_ + c0);
#pragma unroll 4
  for (int j = 0; j < CT_; ++j) {
    size_t idx = base + (size_t)j * C_;
    f32x4 k  = *(const f32x4*)(Kv + idx);
    f32x4 th = *(const f32x4*)(theta + idx);
    f32x4 o;
#pragma unroll
    for (int q = 0; q < 4; ++q) {
      float nu = wrap_neg(th[q]);
      d[q] = (1.f - k[q]) * d[q] + k[q] * nu;
      o[q] = th[q] + d[q];
    }
    __builtin_nontemporal_store(o, (f32x4*)(out0 + idx));
    __builtin_nontemporal_store(Pi4, (f32x4*)(out1 + idx));
  }
}

extern "C" void kernel_launch(void* const* d_in, const int* in_sizes, int n_in,
                              void* d_out, int out_size, void* d_ws, size_t ws_size,
                              hipStream_t stream) {
  const float* theta = (const float*)d_in[0];
  const float* X     = (const float*)d_in[1];
  const float* logPi = (const float*)d_in[2];
  const float* W1    = (const float*)d_in[3];
  const float* b1    = (const float*)d_in[4];
  const float* W2    = (const float*)d_in[5];
  const float* b2    = (const float*)d_in[6];

  float* out = (float*)d_out;
  const size_t S = (size_t)M_ * C_;
  float* out0 = out;
  float* out1 = out + S;
  float* out2 = out + 2 * S;
  float* out3 = out + 3 * S;

  unsigned short* W1T = (unsigned short*)d_ws;           // 131072 ush
  unsigned short* W2T = W1T + (size_t)DM_ * HID_;        // 65536 ush
  float* Ab = (float*)(W2T + (size_t)HID_ * C_);         // B*NC*C f32 each (2 MiB)
  float* Ub = Ab + (size_t)B_ * NC_ * C_;
  float* D0 = Ub + (size_t)B_ * NC_ * C_;

  hipLaunchKernelGGL(k_prep, dim3(768), dim3(256), 0, stream, W1, W2, W1T, W2T);
  hipLaunchKernelGGL(k_mega, dim3(M_ / 16), dim3(512), 0, stream,
                     X, W1T, b1, W2T, b2, logPi, theta, out2, out3, Ab, Ub);
  hipLaunchKernelGGL(k_scan2, dim3(B_ * 32), dim3(256), 0, stream, Ab, Ub, D0);
  hipLaunchKernelGGL(k_scan3, dim3(M_ * C_ / 64 / 256), dim3(256), 0, stream,
                     out2, theta, D0, logPi, out0, out1);
}